// Round 8
// baseline (267.487 us; speedup 1.0000x reference)
//
#include <hip/hip_runtime.h>
#include <math.h>
#include <stdint.h>

#define D_MODEL 2048
#define NEXP    64
#define TOKENS  32768
#define BM      64
#define NT      256
#define NCHUNK  (D_MODEL / 32)   // 64 K-steps of 32
#define TIE_THR 1e-3f            // 3-term split logit err ~3e-5; 30x margin
#define LSTRIDE 66

typedef __attribute__((ext_vector_type(8))) short short8;  // MFMA A/B frag
typedef __attribute__((ext_vector_type(4))) float f32x4;   // MFMA C/D frag
typedef __attribute__((ext_vector_type(4))) int   i32x4;

// hi = fp32 top-16 (RTZ bf16); lo = bf16(f - hi). (hi+lo) rel err <= 2^-16.
__device__ __forceinline__ void split2(float f0, float f1, uint32_t& hw, uint32_t& lw)
{
    const uint32_t u0 = __float_as_uint(f0), u1 = __float_as_uint(f1);
    const uint32_t a0 = u0 & 0xffff0000u, a1 = u1 & 0xffff0000u;
    hw = a1 | (u0 >> 16);
    const float l0 = f0 - __uint_as_float(a0);
    const float l1 = f1 - __uint_as_float(a1);
    lw = (__float_as_uint(l1) & 0xffff0000u) | (__float_as_uint(l0) >> 16);
}

// Two fp32 quads (k+0..3, k+4..7) -> hi/lo bf16 MFMA fragments.
__device__ __forceinline__ void regsplit(const float4 qa, const float4 qb,
                                         short8& h8, short8& l8)
{
    i32x4 hv, lv;
    uint32_t hw, lw;
    split2(qa.x, qa.y, hw, lw); hv[0] = (int)hw; lv[0] = (int)lw;
    split2(qa.z, qa.w, hw, lw); hv[1] = (int)hw; lv[1] = (int)lw;
    split2(qb.x, qb.y, hw, lw); hv[2] = (int)hw; lv[2] = (int)lw;
    split2(qb.z, qb.w, hw, lw); hv[3] = (int)hw; lv[3] = (int)lw;
    h8 = *(short8*)&hv;
    l8 = *(short8*)&lv;
}

// One K=32 step. Current-A in (CA0,CA1); prefetch next-A into (NA0,NA1).
// B (L2-hot) loaded just-in-time; compiler inserts counted waitcnts.
#define ASTEP(c, CA0, CA1, NA0, NA1, DOPREF)                                   \
    do {                                                                       \
        if (DOPREF) {                                                          \
            NA0 = *(const float4*)(xrow + 32 * ((c) + 1));                     \
            NA1 = *(const float4*)(xrow + 32 * ((c) + 1) + 4);                 \
        }                                                                      \
        short8 ah_, al_;                                                       \
        regsplit(CA0, CA1, ah_, al_);                                          \
        _Pragma("unroll")                                                      \
        for (int n = 0; n < 4; ++n) {                                          \
            const float4 qb0 = *(const float4*)(wrow[n] + 32 * (c));           \
            const float4 qb1 = *(const float4*)(wrow[n] + 32 * (c) + 4);       \
            short8 bh_, bl_;                                                   \
            regsplit(qb0, qb1, bh_, bl_);                                      \
            acc[n] = __builtin_amdgcn_mfma_f32_16x16x32_bf16(ah_, bh_, acc[n], 0, 0, 0); \
            acc[n] = __builtin_amdgcn_mfma_f32_16x16x32_bf16(al_, bh_, acc[n], 0, 0, 0); \
            acc[n] = __builtin_amdgcn_mfma_f32_16x16x32_bf16(ah_, bl_, acc[n], 0, 0, 0); \
        }                                                                      \
    } while (0)

__global__ __launch_bounds__(NT, 2)
void router_kernel(const float* __restrict__ x, const float* __restrict__ W,
                   float* __restrict__ out)
{
    __shared__ float logits[BM * LSTRIDE];   // 16.5 KB
    __shared__ float partial[4 * 64];
    __shared__ int   flaglist[BM];
    __shared__ int   nflag;

    const int tid  = threadIdx.x;
    const int lane = tid & 63;
    const int wave = tid >> 6;          // 0..3: m-tile (16 tokens each)
    const int row0 = blockIdx.x * BM;

    // ---- fragment-direct global addressing ----
    // A: lane (fr,h) reads x[row0+16w+fr][32c+8h .. +7]  (one 128B line per row per chunk)
    // B: lane (fr,h) reads W[16n+fr]   [32c+8h .. +7]
    const int fr = lane & 15;
    const int h  = lane >> 4;
    const float* xrow = x + (size_t)(row0 + 16 * wave + fr) * D_MODEL + 8 * h;
    const float* wrow[4];
#pragma unroll
    for (int n = 0; n < 4; ++n)
        wrow[n] = W + (size_t)(16 * n + fr) * D_MODEL + 8 * h;

    f32x4 acc[4] = {};

    // ---- main loop: barrier-free, per-wave independent, A ping-pong ----
    float4 pa0, pa1, qa0, qa1;
    pa0 = *(const float4*)(xrow);
    pa1 = *(const float4*)(xrow + 4);
#pragma unroll 1
    for (int cc = 0; cc < NCHUNK / 2; ++cc) {
        ASTEP(2 * cc,     pa0, pa1, qa0, qa1, 1);
        ASTEP(2 * cc + 1, qa0, qa1, pa0, pa1, (cc < NCHUNK / 2 - 1));
    }

    // ---- epilogue: logits [64][66] in LDS ----
#pragma unroll
    for (int n = 0; n < 4; ++n)
#pragma unroll
        for (int r = 0; r < 4; ++r)
            logits[(16 * wave + 4 * h + r) * LSTRIDE + 16 * n + fr] = acc[n][r];
    if (tid == 0) nflag = 0;
    __syncthreads();

    // ---- top-3 scan, flag near-ties for exact recompute ----
    float m1 = -INFINITY, m2 = -INFINITY, m3 = -INFINITY;
    int   i1 = 0, i2 = 0;
    bool  tie = false;
    if (tid < BM) {
#pragma unroll 8
        for (int e = 0; e < NEXP; ++e) {
            const float v = logits[tid * LSTRIDE + e];
            if (v > m1)      { m3 = m2; m2 = m1; i2 = i1; m1 = v; i1 = e; }
            else if (v > m2) { m3 = m2; m2 = v; i2 = e; }
            else if (v > m3) { m3 = v; }
        }
        tie = (m1 - m2 < TIE_THR) || (m2 - m3 < TIE_THR);
        if (tie) { const int p = atomicAdd(&nflag, 1); flaglist[p] = tid; }
    }
    __syncthreads();

    // ---- exact fp32 cleanup for flagged tokens (~1 per block) ----
    const int nf = nflag;
    for (int f = 0; f < nf; ++f) {
        const int t = flaglist[f];
        const float* xr   = x + (size_t)(row0 + t) * D_MODEL + 512 * wave;
        const float* wrw  = W + (size_t)lane * D_MODEL + 512 * wave;
        float ps = 0.f;
        for (int k = 0; k < 512; k += 4) {
            const float4 xv = *(const float4*)(xr + k);
            const float4 wv = *(const float4*)(wrw + k);
            ps = fmaf(xv.x, wv.x, ps); ps = fmaf(xv.y, wv.y, ps);
            ps = fmaf(xv.z, wv.z, ps); ps = fmaf(xv.w, wv.w, ps);
        }
        partial[wave * 64 + lane] = ps;
        __syncthreads();
        if (tid < NEXP)
            logits[t * LSTRIDE + tid] = (partial[tid] + partial[64 + tid]) +
                                        (partial[128 + tid] + partial[192 + tid]);
        __syncthreads();
    }

    if (tid < BM) {
        if (tie) {   // rescan exact row
            m1 = -INFINITY; m2 = -INFINITY; i1 = 0; i2 = 0;
#pragma unroll 8
            for (int e = 0; e < NEXP; ++e) {
                const float v = logits[tid * LSTRIDE + e];
                if (v > m1)      { m2 = m1; i2 = i1; m1 = v; i1 = e; }
                else if (v > m2) { m2 = v; i2 = e; }
            }
        }
        const float ex = expf(m2 - m1);      // renormalized top-2 softmax
        const float g1 = 1.0f / (1.0f + ex);
        const float g2 = ex * g1;
        const int row = row0 + tid;
        out[(size_t)row * 2 + 0] = g1;
        out[(size_t)row * 2 + 1] = g2;
        out[(size_t)TOKENS * 2 + (size_t)row * 2 + 0] = (float)i1;
        out[(size_t)TOKENS * 2 + (size_t)row * 2 + 1] = (float)i2;
    }
}

extern "C" void kernel_launch(void* const* d_in, const int* in_sizes, int n_in,
                              void* d_out, int out_size, void* d_ws, size_t ws_size,
                              hipStream_t stream) {
    const float* x = (const float*)d_in[0];
    const float* W = (const float*)d_in[1];
    float* out = (float*)d_out;
    router_kernel<<<TOKENS / BM, NT, 0, stream>>>(x, W, out);
}

// Round 9
// 173.769 us; speedup vs baseline: 1.5393x; 1.5393x over previous
//
#include <hip/hip_runtime.h>
#include <math.h>
#include <stdint.h>

#define D_MODEL 2048
#define NEXP    64
#define TOKENS  32768
#define BM      16
#define NCH     64             // K-chunks of 32
#define TIE_THR 1e-3f          // 3-term split logit err ~3e-5; 30x margin
#define LSTRIDE 66

typedef __attribute__((ext_vector_type(8))) short short8;  // MFMA A/B frag
typedef __attribute__((ext_vector_type(4))) float f32x4;   // MFMA C/D frag
typedef __attribute__((ext_vector_type(4))) int   i32x4;

// hi = fp32 top-16 (RTZ bf16); lo = bf16(f - hi). (hi+lo) rel err <= 2^-16.
__device__ __forceinline__ void split2(float f0, float f1, uint32_t& hw, uint32_t& lw)
{
    const uint32_t u0 = __float_as_uint(f0), u1 = __float_as_uint(f1);
    const uint32_t a0 = u0 & 0xffff0000u, a1 = u1 & 0xffff0000u;
    hw = a1 | (u0 >> 16);
    const float l0 = f0 - __uint_as_float(a0);
    const float l1 = f1 - __uint_as_float(a1);
    lw = (__float_as_uint(l1) & 0xffff0000u) | (__float_as_uint(l0) >> 16);
}

// Two fp32 quads (k+0..3, k+4..7) -> hi/lo bf16 MFMA fragments.
__device__ __forceinline__ void regsplit(const float4 qa, const float4 qb,
                                         short8& h8, short8& l8)
{
    i32x4 hv, lv;
    uint32_t hw, lw;
    split2(qa.x, qa.y, hw, lw); hv[0] = (int)hw; lv[0] = (int)lw;
    split2(qa.z, qa.w, hw, lw); hv[1] = (int)hw; lv[1] = (int)lw;
    split2(qb.x, qb.y, hw, lw); hv[2] = (int)hw; lv[2] = (int)lw;
    split2(qb.z, qb.w, hw, lw); hv[3] = (int)hw; lv[3] = (int)lw;
    h8 = *(short8*)&hv;
    l8 = *(short8*)&lv;
}

// ---- pre-kernel: split W into per-fragment bf16 hi/lo blocks in d_ws ----
// Layout (ushort units): group g = c*4+n occupies [g*1024, g*1024+1024):
//   hi frag at g*1024 + lane*8, lo frag at g*1024 + 512 + lane*8.
// Fragment map (matches r4-r8 proven kernels): lane(fr,h) holds
// W[16n+fr][32c+8h .. +7].
__global__ void presplit_kernel(const float* __restrict__ W,
                                ushort* __restrict__ whl)
{
    const int g    = blockIdx.x * 4 + (threadIdx.x >> 6);  // 0..255
    const int lane = threadIdx.x & 63;
    const int c = g >> 2, n = g & 3;
    const int fr = lane & 15, h = lane >> 4;
    const float* wr = W + (size_t)(16 * n + fr) * D_MODEL + 32 * c + 8 * h;
    const float4 qa = *(const float4*)(wr);
    const float4 qb = *(const float4*)(wr + 4);
    short8 hi, lo;
    regsplit(qa, qb, hi, lo);
    *(short8*)(whl + (size_t)g * 1024 + lane * 8)       = hi;
    *(short8*)(whl + (size_t)g * 1024 + 512 + lane * 8) = lo;
}

// One K=32 chunk, static bank K (rule #20). Split current bank first, then
// reuse its registers for the distance-4 prefetch (no clobber hazard).
#define BODY(CC, K, PREF)                                                      \
    do {                                                                       \
        const int c_ = (CC) + (K);                                             \
        short8 ah_, al_;                                                       \
        regsplit(A##K##0, A##K##1, ah_, al_);                                  \
        if (PREF) {                                                            \
            A##K##0 = *(const float4*)(xrow + 32 * (c_ + 4));                  \
            A##K##1 = *(const float4*)(xrow + 32 * (c_ + 4) + 4);              \
        }                                                                      \
        _Pragma("unroll")                                                      \
        for (int n = 0; n < 4; ++n) {                                          \
            const ushort* wp_ = wb + ((size_t)c_ * 4 + n) * 1024;              \
            const i32x4 bhv_ = *(const i32x4*)(wp_);                           \
            const i32x4 blv_ = *(const i32x4*)(wp_ + 512);                     \
            const short8 bh_ = *(const short8*)&bhv_;                          \
            const short8 bl_ = *(const short8*)&blv_;                          \
            acc[n] = __builtin_amdgcn_mfma_f32_16x16x32_bf16(ah_, bh_, acc[n], 0, 0, 0); \
            acc[n] = __builtin_amdgcn_mfma_f32_16x16x32_bf16(al_, bh_, acc[n], 0, 0, 0); \
            acc[n] = __builtin_amdgcn_mfma_f32_16x16x32_bf16(ah_, bl_, acc[n], 0, 0, 0); \
        }                                                                      \
    } while (0)

__global__ __launch_bounds__(64, 4)
void router_main(const float* __restrict__ x, const float* __restrict__ W,
                 const ushort* __restrict__ whl, float* __restrict__ out)
{
    __shared__ float logits[BM * LSTRIDE];   // 4.2 KB
    __shared__ int   flaglist[BM];
    __shared__ int   nflag;

    const int lane = threadIdx.x;            // single wave per block
    const int fr = lane & 15, h = lane >> 4;
    const int row0 = blockIdx.x * BM;

    // A: lane(fr,h) streams x[row0+fr][32c+8h .. +7] (full-line per 16 rows)
    const float* xrow = x + (size_t)(row0 + fr) * D_MODEL + 8 * h;
    const ushort* wb  = whl + lane * 8;

    f32x4 acc[4] = {};

    // ---- prologue: banks 0..3 = chunks 0..3 ----
    float4 A00, A01, A10, A11, A20, A21, A30, A31;
    A00 = *(const float4*)(xrow +  0); A01 = *(const float4*)(xrow +  4);
    A10 = *(const float4*)(xrow + 32); A11 = *(const float4*)(xrow + 36);
    A20 = *(const float4*)(xrow + 64); A21 = *(const float4*)(xrow + 68);
    A30 = *(const float4*)(xrow + 96); A31 = *(const float4*)(xrow + 100);

#pragma unroll 1
    for (int cc = 0; cc < NCH - 4; cc += 4) {
        BODY(cc, 0, 1); BODY(cc, 1, 1); BODY(cc, 2, 1); BODY(cc, 3, 1);
    }
    BODY(NCH - 4, 0, 0); BODY(NCH - 4, 1, 0);
    BODY(NCH - 4, 2, 0); BODY(NCH - 4, 3, 0);

    // ---- epilogue: logits [16][66] (C/D map: col=lane&15=expert, row=4h+r=token) ----
#pragma unroll
    for (int n = 0; n < 4; ++n)
#pragma unroll
        for (int r = 0; r < 4; ++r)
            logits[(4 * h + r) * LSTRIDE + 16 * n + fr] = acc[n][r];
    if (lane == 0) nflag = 0;
    __syncthreads();

    // ---- top-3 scan, flag near-ties for exact recompute ----
    float m1 = -INFINITY, m2 = -INFINITY, m3 = -INFINITY;
    int   i1 = 0, i2 = 0;
    bool  tie = false;
    if (lane < BM) {
#pragma unroll 8
        for (int e = 0; e < NEXP; ++e) {
            const float v = logits[lane * LSTRIDE + e];
            if (v > m1)      { m3 = m2; m2 = m1; i2 = i1; m1 = v; i1 = e; }
            else if (v > m2) { m3 = m2; m2 = v; i2 = e; }
            else if (v > m3) { m3 = v; }
        }
        tie = (m1 - m2 < TIE_THR) || (m2 - m3 < TIE_THR);
        if (tie) { const int p = atomicAdd(&nflag, 1); flaglist[p] = lane; }
    }
    __syncthreads();

    // ---- exact fp32 cleanup (rare): lane = expert, full-K dot ----
    const int nf = nflag;
    for (int f = 0; f < nf; ++f) {
        const int t = flaglist[f];
        const float* xr = x + (size_t)(row0 + t) * D_MODEL;
        const float* wr = W + (size_t)lane * D_MODEL;
        float ps = 0.f;
        for (int k = 0; k < D_MODEL; k += 4) {
            const float4 xv = *(const float4*)(xr + k);
            const float4 wv = *(const float4*)(wr + k);
            ps = fmaf(xv.x, wv.x, ps); ps = fmaf(xv.y, wv.y, ps);
            ps = fmaf(xv.z, wv.z, ps); ps = fmaf(xv.w, wv.w, ps);
        }
        logits[t * LSTRIDE + lane] = ps;
    }
    __syncthreads();

    if (lane < BM) {
        if (tie) {   // rescan exact row
            m1 = -INFINITY; m2 = -INFINITY; i1 = 0; i2 = 0;
#pragma unroll 8
            for (int e = 0; e < NEXP; ++e) {
                const float v = logits[lane * LSTRIDE + e];
                if (v > m1)      { m2 = m1; i2 = i1; m1 = v; i1 = e; }
                else if (v > m2) { m2 = v; i2 = e; }
            }
        }
        const float ex = expf(m2 - m1);      // renormalized top-2 softmax
        const float g1 = 1.0f / (1.0f + ex);
        const float g2 = ex * g1;
        const int row = row0 + lane;
        out[(size_t)row * 2 + 0] = g1;
        out[(size_t)row * 2 + 1] = g2;
        out[(size_t)TOKENS * 2 + (size_t)row * 2 + 0] = (float)i1;
        out[(size_t)TOKENS * 2 + (size_t)row * 2 + 1] = (float)i2;
    }
}

extern "C" void kernel_launch(void* const* d_in, const int* in_sizes, int n_in,
                              void* d_out, int out_size, void* d_ws, size_t ws_size,
                              hipStream_t stream) {
    const float* x = (const float*)d_in[0];
    const float* W = (const float*)d_in[1];
    float* out  = (float*)d_out;
    ushort* whl = (ushort*)d_ws;     // 512 KB of scratch
    presplit_kernel<<<64, 256, 0, stream>>>(W, whl);
    router_main<<<TOKENS / BM, 64, 0, stream>>>(x, W, whl, out);
}